// Round 9
// baseline (230.028 us; speedup 1.0000x reference)
//
#include <hip/hip_runtime.h>

// YOLO v1 loss — R6: two-kernel (no fences) + higher occupancy.
// R5 post-mortem: part1 73us @ 2.6 TB/s effective (94MB fetch + 98MB
// restore-dirt writeback), VALUBusy 4.3%, Occupancy 21.6% (41.5KB LDS ->
// 3 blocks/CU). Theory: miss-latency underutilization -> halve RPB so
// 20.5KB LDS -> 7 blocks/CU = 28 waves, deeper outstanding-miss pool.
// Fixed ~133us of bench dur is the harness's 193MB d_in restore (not ours).
// B=16384, S2=49, C=30  ->  N = 802816 rows of 30 f32.
#define NROWS 802816
#define RPB   256          // rows per block (kernel1)
#define NB    (NROWS/RPB)  // 3136 blocks (exact)
#define BS    256          // threads per block
#define SCAN_N 4096        // next pow2 >= NB

struct RowRes { float term; bool mask; };

__device__ __forceinline__ float iou_f(float ax, float ay, float aX, float aY,
                                       float bx, float by, float bX, float bY) {
    float ltx = fmaxf(ax, bx), lty = fmaxf(ay, by);
    float rbx = fminf(aX, bX), rby = fminf(aY, bY);
    float w = fmaxf(rbx - ltx, 0.0f), h = fmaxf(rby - lty, 0.0f);
    float inter = w * h;
    float aa = (aX - ax) * (aY - ay);
    float ab = (bX - bx) * (bY - by);
    return inter / (aa + ab - inter);
}

// Loss term from the 10 leading floats of p-row (a0..a4) and t-row (b0..b4).
__device__ __forceinline__ RowRes term_from(float2 a0, float2 a1, float2 a2,
                                            float2 a3, float2 a4, float2 b0,
                                            float2 b1, float2 b2, float2 b3,
                                            float2 b4) {
    bool mask = (b2.x == 1.0f); // t[:,4]
    float i0 = iou_f(a0.x, a0.y, a1.x, a1.y, b0.x, b0.y, b1.x, b1.y);
    float i1 = iou_f(a2.y, a3.x, a3.y, a4.x, b0.x, b0.y, b1.x, b1.y);
    bool ch = i1 > i0;
    float miou = fmaxf(i0, i1);

    float px = ch ? a2.y : a0.x;
    float py = ch ? a3.x : a0.y;
    float pw = ch ? a3.y : a1.x;
    float ph = ch ? a4.x : a1.y;
    float tx = ch ? b2.y : b0.x;
    float ty = ch ? b3.x : b0.y;
    float tw = ch ? b3.y : b1.x;
    float th = ch ? b4.x : b1.y;
    float cf = ch ? a4.y : a2.y; // p9 : p5

    float dx = px - tx, dy = py - ty, dw = pw - tw, dh = ph - th;
    float dc = cf - miou;
    RowRes rr;
    rr.term = dx * dx + dy * dy + dw * dw + dh * dh + 2.0f * dc * dc;
    rr.mask = mask;
    return rr;
}

// Direct-from-global row term (kernel2's boundary recompute only).
__device__ __forceinline__ RowRes row_term(const float* __restrict__ P,
                                           const float* __restrict__ T, int r) {
    const float2* pr = reinterpret_cast<const float2*>(P + (size_t)r * 30);
    const float2* tr = reinterpret_cast<const float2*>(T + (size_t)r * 30);
    return term_from(pr[0], pr[1], pr[2], pr[3], pr[4],
                     tr[0], tr[1], tr[2], tr[3], tr[4]);
}

// ---- kernel 1: per-block masked count + masked term sum (no fences) ----
__global__ __launch_bounds__(BS) void yolo_part1(
        const float* __restrict__ P, const float* __restrict__ T,
        float* __restrict__ sums, int* __restrict__ counts) {
    __shared__ __align__(16) float2 sP[RPB * 5];   // 10240 B
    __shared__ __align__(16) float2 sT[RPB * 5];   // 10240 B
    __shared__ float s_f[4];
    __shared__ int   s_i[4];

    const int tid = threadIdx.x;
    const int b = blockIdx.x;
    const int lane = tid & 63, wv = tid >> 6;

    const float2* Pg = reinterpret_cast<const float2*>(P);
    const float2* Tg = reinterpret_cast<const float2*>(T);

    // Stage needed columns (first 5 float2 of each 15-float2 row):
    // 10 independent near-coalesced loads per thread before one barrier.
    const size_t base2 = (size_t)b * RPB * 15;
#pragma unroll
    for (int k = 0; k < RPB * 5 / BS; ++k) {       // 5 iterations
        unsigned n = tid + k * BS;
        unsigned row = n / 5u, c = n - row * 5u;
        size_t g = base2 + row * 15u + c;
        sP[n] = Pg[g];
        sT[n] = Tg[g];
    }
    __syncthreads();

    // one row per thread
    RowRes rr = term_from(sP[tid * 5 + 0], sP[tid * 5 + 1], sP[tid * 5 + 2],
                          sP[tid * 5 + 3], sP[tid * 5 + 4],
                          sT[tid * 5 + 0], sT[tid * 5 + 1], sT[tid * 5 + 2],
                          sT[tid * 5 + 3], sT[tid * 5 + 4]);
    float acc = rr.mask ? rr.term : 0.0f;
    int   cnt = rr.mask ? 1 : 0;
#pragma unroll
    for (int o = 32; o > 0; o >>= 1) {
        acc += __shfl_down(acc, o, 64);
        cnt += __shfl_down(cnt, o, 64);
    }
    if (lane == 0) { s_f[wv] = acc; s_i[wv] = cnt; }
    __syncthreads();
    if (tid == 0) {
        sums[b]   = s_f[0] + s_f[1] + s_f[2] + s_f[3];
        counts[b] = s_i[0] + s_i[1] + s_i[2] + s_i[3];
    }
}

// ---- kernel 2: one block — scan, select, boundary recompute, final sum ----
__global__ __launch_bounds__(BS) void yolo_part2(
        const float* __restrict__ P, const float* __restrict__ T,
        const float* __restrict__ sums, const int* __restrict__ counts,
        float* __restrict__ out) {
    __shared__ int sA[SCAN_N], sB[SCAN_N];         // 32 KB
    __shared__ float s_f[4], s_f2[4];
    __shared__ int   s_i[4];
    __shared__ int   s_bb, s_take;

    const int tid = threadIdx.x;
    const int lane = tid & 63, wv = tid >> 6;

    // inclusive scan of counts (Hillis-Steele over 4096, 256 threads)
    for (int i = tid; i < SCAN_N; i += BS) sA[i] = (i < NB) ? counts[i] : 0;
    __syncthreads();
    int* src = sA; int* dst = sB;
    for (int off = 1; off < SCAN_N; off <<= 1) {
        for (int i = tid; i < SCAN_N; i += BS) {
            int v = src[i];
            if (i >= off) v += src[i - off];
            dst[i] = v;
        }
        __syncthreads();
        int* t_ = src; src = dst; dst = t_;
    }
    const int n  = src[SCAN_N - 1];
    const int nh = n >> 1;                         // n // 2

    if (tid == 0) { s_bb = -1; s_take = 0; }
    __syncthreads();

    // full blocks with prefix+count <= nh contribute sums[i]; <=1 is partial
    float fs = 0.0f;
    for (int i = tid; i < NB; i += BS) {
        int incl = src[i];
        int c = incl - ((i > 0) ? src[i - 1] : 0);
        int pfx = incl - c;
        int take = nh - pfx;
        take = take < 0 ? 0 : (take > c ? c : take);
        if (take == c)      fs += sums[i];
        else if (take > 0) { s_bb = i; s_take = take; }  // exactly one
    }
    __syncthreads();
#pragma unroll
    for (int o = 32; o > 0; o >>= 1) fs += __shfl_down(fs, o, 64);
    if (lane == 0) s_f[wv] = fs;
    __syncthreads();

    // boundary block: recompute its 256 rows in order, take first `take` masked
    const int bb = s_bb, take = s_take;
    float psum = 0.0f;
    if (bb >= 0) {                                 // uniform branch
        RowRes rr = row_term(P, T, bb * RPB + tid);
        unsigned long long bal = __ballot(rr.mask);
        if (lane == 0) s_i[wv] = __popcll(bal);
        __syncthreads();
        int off = 0;
        for (int w = 0; w < wv; ++w) off += s_i[w];
        int rk = off + __popcll(bal & ((1ull << lane) - 1ull));
        if (rr.mask && rk < take) psum += rr.term;
    }
#pragma unroll
    for (int o = 32; o > 0; o >>= 1) psum += __shfl_down(psum, o, 64);
    if (lane == 0) s_f2[wv] = psum;
    __syncthreads();

    if (tid == 0) {
        float total = s_f[0] + s_f[1] + s_f[2] + s_f[3]
                    + s_f2[0] + s_f2[1] + s_f2[2] + s_f2[3];
        out[0] = 5.0f * total;                     // LAMBDA_COORD * (...)
    }
}

extern "C" void kernel_launch(void* const* d_in, const int* in_sizes, int n_in,
                              void* d_out, int out_size, void* d_ws, size_t ws_size,
                              hipStream_t stream) {
    const float* P = (const float*)d_in[0];        // predictions f32
    const float* T = (const float*)d_in[1];        // targets f32
    float* out = (float*)d_out;

    float* sums   = (float*)d_ws;                  // NB floats (fully overwritten)
    int*   counts = (int*)((char*)d_ws + NB * 4);  // NB ints   (fully overwritten)

    yolo_part1<<<NB, BS, 0, stream>>>(P, T, sums, counts);
    yolo_part2<<<1, BS, 0, stream>>>(P, T, sums, counts, out);
}

// Round 10
// 226.044 us; speedup vs baseline: 1.0176x; 1.0176x over previous
//
#include <hip/hip_runtime.h>

// YOLO v1 loss — R10: full-line DENSE streaming stage (m13 copy pattern).
// Ladder: R1 scattered 8B = 1.2 TB/s; R5/R9 column-compact staged = 2.7 TB/s;
// R9 occupancy 21.6->50% = NO change => shared-resource cap, not latency depth.
// Hypothesis: achieved BW ~ request density (bytes/wave-instr x line util).
// Fix: stage the full 30KB/tensor block chunk as flat coalesced float4
// (1KB/wave-instr, 100% line utilization) — every touched line is needed
// anyway (80B gaps < 128B lines). LDS 60KB -> 2 blocks/CU (fine per R9).
// B=16384, S2=49, C=30  ->  N = 802816 rows of 30 f32.
#define NROWS 802816
#define RPB   256          // rows per block (kernel1)
#define NB    (NROWS/RPB)  // 3136 blocks (exact)
#define BS    256          // threads per block
#define SCAN_N 4096        // next pow2 >= NB
#define F4PB  (RPB*30/4)   // 1920 float4 per tensor per block

struct RowRes { float term; bool mask; };

__device__ __forceinline__ float iou_f(float ax, float ay, float aX, float aY,
                                       float bx, float by, float bX, float bY) {
    float ltx = fmaxf(ax, bx), lty = fmaxf(ay, by);
    float rbx = fminf(aX, bX), rby = fminf(aY, bY);
    float w = fmaxf(rbx - ltx, 0.0f), h = fmaxf(rby - lty, 0.0f);
    float inter = w * h;
    float aa = (aX - ax) * (aY - ay);
    float ab = (bX - bx) * (bY - by);
    return inter / (aa + ab - inter);
}

// Loss term from the 10 leading floats of p-row (a0..a4) and t-row (b0..b4).
__device__ __forceinline__ RowRes term_from(float2 a0, float2 a1, float2 a2,
                                            float2 a3, float2 a4, float2 b0,
                                            float2 b1, float2 b2, float2 b3,
                                            float2 b4) {
    bool mask = (b2.x == 1.0f); // t[:,4]
    float i0 = iou_f(a0.x, a0.y, a1.x, a1.y, b0.x, b0.y, b1.x, b1.y);
    float i1 = iou_f(a2.y, a3.x, a3.y, a4.x, b0.x, b0.y, b1.x, b1.y);
    bool ch = i1 > i0;
    float miou = fmaxf(i0, i1);

    float px = ch ? a2.y : a0.x;
    float py = ch ? a3.x : a0.y;
    float pw = ch ? a3.y : a1.x;
    float ph = ch ? a4.x : a1.y;
    float tx = ch ? b2.y : b0.x;
    float ty = ch ? b3.x : b0.y;
    float tw = ch ? b3.y : b1.x;
    float th = ch ? b4.x : b1.y;
    float cf = ch ? a4.y : a2.y; // p9 : p5

    float dx = px - tx, dy = py - ty, dw = pw - tw, dh = ph - th;
    float dc = cf - miou;
    RowRes rr;
    rr.term = dx * dx + dy * dy + dw * dw + dh * dh + 2.0f * dc * dc;
    rr.mask = mask;
    return rr;
}

// Direct-from-global row term (kernel2's boundary recompute only).
__device__ __forceinline__ RowRes row_term(const float* __restrict__ P,
                                           const float* __restrict__ T, int r) {
    const float2* pr = reinterpret_cast<const float2*>(P + (size_t)r * 30);
    const float2* tr = reinterpret_cast<const float2*>(T + (size_t)r * 30);
    return term_from(pr[0], pr[1], pr[2], pr[3], pr[4],
                     tr[0], tr[1], tr[2], tr[3], tr[4]);
}

// ---- kernel 1: per-block masked count + masked term sum ----
__global__ __launch_bounds__(BS) void yolo_part1(
        const float* __restrict__ P, const float* __restrict__ T,
        float* __restrict__ sums, int* __restrict__ counts) {
    __shared__ __align__(16) float4 sP4[F4PB];     // 30720 B (full rows)
    __shared__ __align__(16) float4 sT4[F4PB];     // 30720 B
    __shared__ float s_f[4];
    __shared__ int   s_i[4];

    const int tid = threadIdx.x;
    const int b = blockIdx.x;
    const int lane = tid & 63, wv = tid >> 6;

    // Flat dense stream: 1920 float4 per tensor, consecutive lanes ->
    // consecutive 16B -> 1KB per wave-instruction, 100% line utilization.
    const float4* Pg4 = reinterpret_cast<const float4*>(P) + (size_t)b * F4PB;
    const float4* Tg4 = reinterpret_cast<const float4*>(T) + (size_t)b * F4PB;
#pragma unroll
    for (int k = 0; k < F4PB / BS; ++k) {          // 7 full iterations
        int n = tid + k * BS;
        sP4[n] = Pg4[n];
        sT4[n] = Tg4[n];
    }
    if (tid < F4PB - (F4PB / BS) * BS) {           // remaining 128
        int n = tid + (F4PB / BS) * BS;
        sP4[n] = Pg4[n];
        sT4[n] = Tg4[n];
    }
    __syncthreads();

    // one row per thread: 15 float2 per row in LDS, need first 5 of each
    const float2* sP = reinterpret_cast<const float2*>(sP4);
    const float2* sT = reinterpret_cast<const float2*>(sT4);
    RowRes rr = term_from(sP[tid * 15 + 0], sP[tid * 15 + 1], sP[tid * 15 + 2],
                          sP[tid * 15 + 3], sP[tid * 15 + 4],
                          sT[tid * 15 + 0], sT[tid * 15 + 1], sT[tid * 15 + 2],
                          sT[tid * 15 + 3], sT[tid * 15 + 4]);
    float acc = rr.mask ? rr.term : 0.0f;
    int   cnt = rr.mask ? 1 : 0;
#pragma unroll
    for (int o = 32; o > 0; o >>= 1) {
        acc += __shfl_down(acc, o, 64);
        cnt += __shfl_down(cnt, o, 64);
    }
    if (lane == 0) { s_f[wv] = acc; s_i[wv] = cnt; }
    __syncthreads();
    if (tid == 0) {
        sums[b]   = s_f[0] + s_f[1] + s_f[2] + s_f[3];
        counts[b] = s_i[0] + s_i[1] + s_i[2] + s_i[3];
    }
}

// ---- kernel 2: one block — scan, select, boundary recompute, final sum ----
__global__ __launch_bounds__(BS) void yolo_part2(
        const float* __restrict__ P, const float* __restrict__ T,
        const float* __restrict__ sums, const int* __restrict__ counts,
        float* __restrict__ out) {
    __shared__ int sA[SCAN_N], sB[SCAN_N];         // 32 KB
    __shared__ float s_f[4], s_f2[4];
    __shared__ int   s_i[4];
    __shared__ int   s_bb, s_take;

    const int tid = threadIdx.x;
    const int lane = tid & 63, wv = tid >> 6;

    // inclusive scan of counts (Hillis-Steele over 4096, 256 threads)
    for (int i = tid; i < SCAN_N; i += BS) sA[i] = (i < NB) ? counts[i] : 0;
    __syncthreads();
    int* src = sA; int* dst = sB;
    for (int off = 1; off < SCAN_N; off <<= 1) {
        for (int i = tid; i < SCAN_N; i += BS) {
            int v = src[i];
            if (i >= off) v += src[i - off];
            dst[i] = v;
        }
        __syncthreads();
        int* t_ = src; src = dst; dst = t_;
    }
    const int n  = src[SCAN_N - 1];
    const int nh = n >> 1;                         // n // 2

    if (tid == 0) { s_bb = -1; s_take = 0; }
    __syncthreads();

    // full blocks with prefix+count <= nh contribute sums[i]; <=1 is partial
    float fs = 0.0f;
    for (int i = tid; i < NB; i += BS) {
        int incl = src[i];
        int c = incl - ((i > 0) ? src[i - 1] : 0);
        int pfx = incl - c;
        int take = nh - pfx;
        take = take < 0 ? 0 : (take > c ? c : take);
        if (take == c)      fs += sums[i];
        else if (take > 0) { s_bb = i; s_take = take; }  // exactly one
    }
    __syncthreads();
#pragma unroll
    for (int o = 32; o > 0; o >>= 1) fs += __shfl_down(fs, o, 64);
    if (lane == 0) s_f[wv] = fs;
    __syncthreads();

    // boundary block: recompute its 256 rows in order, take first `take` masked
    const int bb = s_bb, take = s_take;
    float psum = 0.0f;
    if (bb >= 0) {                                 // uniform branch
        RowRes rr = row_term(P, T, bb * RPB + tid);
        unsigned long long bal = __ballot(rr.mask);
        if (lane == 0) s_i[wv] = __popcll(bal);
        __syncthreads();
        int off = 0;
        for (int w = 0; w < wv; ++w) off += s_i[w];
        int rk = off + __popcll(bal & ((1ull << lane) - 1ull));
        if (rr.mask && rk < take) psum += rr.term;
    }
#pragma unroll
    for (int o = 32; o > 0; o >>= 1) psum += __shfl_down(psum, o, 64);
    if (lane == 0) s_f2[wv] = psum;
    __syncthreads();

    if (tid == 0) {
        float total = s_f[0] + s_f[1] + s_f[2] + s_f[3]
                    + s_f2[0] + s_f2[1] + s_f2[2] + s_f2[3];
        out[0] = 5.0f * total;                     // LAMBDA_COORD * (...)
    }
}

extern "C" void kernel_launch(void* const* d_in, const int* in_sizes, int n_in,
                              void* d_out, int out_size, void* d_ws, size_t ws_size,
                              hipStream_t stream) {
    const float* P = (const float*)d_in[0];        // predictions f32
    const float* T = (const float*)d_in[1];        // targets f32
    float* out = (float*)d_out;

    float* sums   = (float*)d_ws;                  // NB floats (fully overwritten)
    int*   counts = (int*)((char*)d_ws + NB * 4);  // NB ints   (fully overwritten)

    yolo_part1<<<NB, BS, 0, stream>>>(P, T, sums, counts);
    yolo_part2<<<1, BS, 0, stream>>>(P, T, sums, counts, out);
}